// Round 12
// baseline (153.513 us; speedup 1.0000x reference)
//
#include <hip/hip_runtime.h>
#include <hip/hip_bf16.h>
#include <stdint.h>

#define D_MODEL 1024
#define NHEAD 8
#define HDIM 128
#define BATCH 2
#define SEQ 2048
#define MTOT (BATCH*SEQ)   // 4096
#define KVBLK 64
#define NT (SEQ/KVBLK)     // 32

typedef __attribute__((ext_vector_type(4))) float f32x4;
typedef __attribute__((ext_vector_type(8))) short bf16x8;

// XOR swizzle: LDS(row, c) holds element (row, c ^ ((row&7)<<4)). Involution,
// used identically on the pre-swizzled global source and the ds_read side (G21).
__device__ __forceinline__ uint32_t swz128(uint32_t row, uint32_t cb) {
  return row * 128u + (cb ^ ((row & 7u) << 4));
}
__device__ __forceinline__ uint32_t swz256(uint32_t row, uint32_t cb) {
  return row * 256u + (cb ^ ((row & 7u) << 4));
}

// async global->LDS, 16B per lane
__device__ __forceinline__ void gload16(void* lds, const void* g) {
  __builtin_amdgcn_global_load_lds(
      reinterpret_cast<const __attribute__((address_space(1))) uint32_t*>(
          reinterpret_cast<uintptr_t>(g)),
      reinterpret_cast<__attribute__((address_space(3))) uint32_t*>(
          (uint32_t)reinterpret_cast<uintptr_t>(lds)),
      16, 0, 0);
}

// Counted barriers (T4).
__device__ __forceinline__ void barrier_lgkm() {
  asm volatile("s_waitcnt lgkmcnt(0)\n\ts_barrier" ::: "memory");
}
__device__ __forceinline__ void barrier_vm16() {
  asm volatile("s_waitcnt vmcnt(16) lgkmcnt(0)\n\ts_barrier" ::: "memory");
}
__device__ __forceinline__ void barrier_vm0() {
  asm volatile("s_waitcnt vmcnt(0) lgkmcnt(0)\n\ts_barrier" ::: "memory");
}

// ---------------- prep: cast q/k/v fp32->bf16 (blocks [0,6144)) AND
// transpose+cast 4 weights (blocks [6144,10240)), one launch ----------------
__global__ __launch_bounds__(256)
void prep(const float* __restrict__ q, const float* __restrict__ k,
          const float* __restrict__ v, __hip_bfloat16* __restrict__ qkv_out,
          const float* __restrict__ w0, const float* __restrict__ w1,
          const float* __restrict__ w2, const float* __restrict__ w3,
          __hip_bfloat16* __restrict__ t0, __hip_bfloat16* __restrict__ t1,
          __hip_bfloat16* __restrict__ t2, __hip_bfloat16* __restrict__ t3) {
  const int bid = blockIdx.x;
  const int tid = threadIdx.x;
  if (bid < 6144) {
    const int which = bid >> 11;          // 0..2
    const int blk = bid & 2047;
    const float* src = which == 0 ? q : (which == 1 ? k : v);
    const size_t NE = (size_t)MTOT * D_MODEL;
    size_t i = ((size_t)blk * 256 + tid) * 8;
    float4 a = *reinterpret_cast<const float4*>(src + i);
    float4 b = *reinterpret_cast<const float4*>(src + i + 4);
    __hip_bfloat16 o[8] = {__float2bfloat16(a.x), __float2bfloat16(a.y),
                           __float2bfloat16(a.z), __float2bfloat16(a.w),
                           __float2bfloat16(b.x), __float2bfloat16(b.y),
                           __float2bfloat16(b.z), __float2bfloat16(b.w)};
    *reinterpret_cast<uint4*>(qkv_out + which * NE + i) =
        *reinterpret_cast<const uint4*>(o);
  } else {
    const int rb = bid - 6144;
    const int z = rb >> 10;               // 0..3
    const int rem = rb & 1023;
    const float* W = z == 0 ? w0 : z == 1 ? w1 : z == 2 ? w2 : w3;
    __hip_bfloat16* Wt = z == 0 ? t0 : z == 1 ? t1 : z == 2 ? t2 : t3;
    __shared__ float t[32][33];
    const int x = tid & 31, y = tid >> 5;  // 32 x 8
    const int n0 = (rem & 31) * 32, k0 = (rem >> 5) * 32;
#pragma unroll
    for (int i = 0; i < 4; ++i)
      t[y + i * 8][x] = W[(size_t)(k0 + y + i * 8) * D_MODEL + n0 + x];
    __syncthreads();
#pragma unroll
    for (int i = 0; i < 4; ++i)
      Wt[(size_t)(n0 + y + i * 8) * D_MODEL + k0 + x] = __float2bfloat16(t[x][y + i * 8]);
  }
}

struct GemmArgs {
  const __hip_bfloat16* A;   // [M][K]
  const __hip_bfloat16* B;   // [N][K]  (W^T)
  const float* bias;         // [N]
  void* out;
  int mode;  // 0: bf16 [bh][s][hd]; 1: bf16 [bh][hd][s]; 2: fp32 [row][col]
};

// ---------------- 128x128 bf16 GEMM, double-buffered prefetch K-loop (r8-proven) ----------------
__global__ __launch_bounds__(256)
void gemm_gl(GemmArgs g0, GemmArgs g1, GemmArgs g2, int K) {
  __shared__ char lds[2][32768];   // per buf: A 16KB | B 16KB
  GemmArgs ga = blockIdx.z == 0 ? g0 : (blockIdx.z == 1 ? g1 : g2);

  const int tid = threadIdx.x, lane = tid & 63, wid = tid >> 6;
  const int lrow = lane & 15, lko = (lane >> 4) * 8, rbase = (lane >> 4) * 4;
  const int m0 = blockIdx.x * 128, n0 = blockIdx.y * 128;
  const size_t ldb = (size_t)K * 2;

  const int srow = lane >> 3;                       // row within 8-row call
  const int sca = ((lane & 7) * 16) ^ (srow << 4);  // pre-swizzled source col
  const char* Ab = (const char*)ga.A + (size_t)(m0 + wid * 32 + srow) * ldb + sca;
  const char* Bb = (const char*)ga.B + (size_t)(n0 + wid * 32 + srow) * ldb + sca;
  const int sdst = wid * 32 * 128;                  // wave's LDS row base (bytes)

  f32x4 acc[4][4];
  const f32x4 fz = {0.f, 0.f, 0.f, 0.f};
#pragma unroll
  for (int m = 0; m < 4; ++m)
#pragma unroll
    for (int n = 0; n < 4; ++n) acc[m][n] = fz;

  const int wm = (wid >> 1) * 64, wn = (wid & 1) * 64;
  const int NKT = K >> 6;

  // prologue: stage tile 0 into buf 0
#pragma unroll
  for (int i = 0; i < 4; ++i) {
    gload16(&lds[0][sdst + i * 8 * 128], Ab + (size_t)i * 8 * ldb);
    gload16(&lds[0][16384 + sdst + i * 8 * 128], Bb + (size_t)i * 8 * ldb);
  }
  barrier_vm0();   // tile 0 ready

  for (int kt = 0; kt < NKT; ++kt) {
    const int c = kt & 1;
    if (kt + 1 < NKT) {  // prefetch next tile into other buffer
      const size_t koff = (size_t)(kt + 1) * 128;
#pragma unroll
      for (int i = 0; i < 4; ++i) {
        gload16(&lds[c ^ 1][sdst + i * 8 * 128], Ab + (size_t)i * 8 * ldb + koff);
        gload16(&lds[c ^ 1][16384 + sdst + i * 8 * 128], Bb + (size_t)i * 8 * ldb + koff);
      }
    }
    const char* lA = lds[c];
    const char* lB = lds[c] + 16384;
#pragma unroll
    for (int kk = 0; kk < 64; kk += 32) {
      bf16x8 af[4], bf[4];
#pragma unroll
      for (int m = 0; m < 4; ++m)
        af[m] = *reinterpret_cast<const bf16x8*>(&lA[swz128(wm + m * 16 + lrow, (kk + lko) * 2)]);
#pragma unroll
      for (int n = 0; n < 4; ++n)
        bf[n] = *reinterpret_cast<const bf16x8*>(&lB[swz128(wn + n * 16 + lrow, (kk + lko) * 2)]);
      __builtin_amdgcn_s_setprio(1);
#pragma unroll
      for (int m = 0; m < 4; ++m)
#pragma unroll
        for (int n = 0; n < 4; ++n)
          acc[m][n] = __builtin_amdgcn_mfma_f32_16x16x32_bf16(af[m], bf[n], acc[m][n], 0, 0, 0);
      __builtin_amdgcn_s_setprio(0);
    }
    barrier_vm0();  // prefetch complete + all ds_reads retired -> bufs swap safely
  }

  if (ga.mode == 0) {
#pragma unroll
    for (int m = 0; m < 4; ++m)
#pragma unroll
      for (int n = 0; n < 4; ++n) {
        const int col = n0 + wn + n * 16 + lrow;
        const float bv = ga.bias[col];
        const int h = col >> 7, hd = col & 127;
#pragma unroll
        for (int r = 0; r < 4; ++r) {
          const int row = m0 + wm + m * 16 + rbase + r;
          const int b = row >> 11, s = row & 2047;
          reinterpret_cast<__hip_bfloat16*>(ga.out)[((size_t)(b * NHEAD + h) * SEQ + s) * HDIM + hd] =
              __float2bfloat16(acc[m][n][r] + bv);
        }
      }
  } else {
#pragma unroll
    for (int m = 0; m < 4; ++m)
#pragma unroll
      for (int n = 0; n < 4; ++n) {
        const int col = n0 + wn + n * 16 + lrow;
        const float bv = ga.bias[col];
        const int h = col >> 7, hd = col & 127;
#pragma unroll
        for (int r = 0; r < 4; ++r) {
          const int row = m0 + wm + m * 16 + rbase + r;
          const int b = row >> 11, s = row & 2047;
          reinterpret_cast<__hip_bfloat16*>(ga.out)[((size_t)(b * NHEAD + h) * HDIM + hd) * SEQ + s] =
              __float2bfloat16(acc[m][n][r] + bv);
        }
      }
  }
}

// ---------------- 128x64 bf16 GEMM for out-projection (fp32 out) ----------------
// 256 thr / 4 waves (2x2), per wave 64x32 = acc[4][2]. LDS 48KB dbuf
// (A 2x16KB | B 2x8KB) -> 3 blocks/CU capacity; grid (32,16)=512 blocks =
// 2+/CU -> 2-3 waves/SIMD (the QKV regime), vs the old 1 wave/SIMD at 1 block/CU.
__global__ __launch_bounds__(256)
void gemm_out(const __hip_bfloat16* __restrict__ A,   // [M][K] (ctx)
              const __hip_bfloat16* __restrict__ Bt,  // [N][K] (Wo^T)
              const float* __restrict__ bias,
              float* __restrict__ out, int K) {
  __shared__ char lds[2][24576];   // per buf: A 16KB | B 8KB

  const int tid = threadIdx.x, lane = tid & 63, wid = tid >> 6;
  const int lrow = lane & 15, lko = (lane >> 4) * 8, rbase = (lane >> 4) * 4;
  const int m0 = blockIdx.x * 128, n0 = blockIdx.y * 64;
  const size_t ldb = (size_t)K * 2;

  const int srow = lane >> 3;                       // row within 8-row call
  const int sca = ((lane & 7) * 16) ^ (srow << 4);  // pre-swizzled source col
  const char* Ab = (const char*)A + (size_t)(m0 + wid * 32 + srow) * ldb + sca;
  const char* Bb = (const char*)Bt + (size_t)(n0 + wid * 16 + srow) * ldb + sca;
  const int adst = wid * 32 * 128;   // A: wave rows [32w,32w+32)
  const int bdst = wid * 16 * 128;   // B: wave rows [16w,16w+16)

  f32x4 acc[4][2];
  const f32x4 fz = {0.f, 0.f, 0.f, 0.f};
#pragma unroll
  for (int m = 0; m < 4; ++m)
#pragma unroll
    for (int n = 0; n < 2; ++n) acc[m][n] = fz;

  const int wm = (wid >> 1) * 64, wn = (wid & 1) * 32;
  const int NKT = K >> 6;

  // prologue: stage tile 0 into buf 0
#pragma unroll
  for (int i = 0; i < 4; ++i)
    gload16(&lds[0][adst + i * 1024], Ab + (size_t)i * 8 * ldb);
#pragma unroll
  for (int i = 0; i < 2; ++i)
    gload16(&lds[0][16384 + bdst + i * 1024], Bb + (size_t)i * 8 * ldb);
  barrier_vm0();

  for (int kt = 0; kt < NKT; ++kt) {
    const int c = kt & 1;
    if (kt + 1 < NKT) {
      const size_t koff = (size_t)(kt + 1) * 128;
#pragma unroll
      for (int i = 0; i < 4; ++i)
        gload16(&lds[c ^ 1][adst + i * 1024], Ab + (size_t)i * 8 * ldb + koff);
#pragma unroll
      for (int i = 0; i < 2; ++i)
        gload16(&lds[c ^ 1][16384 + bdst + i * 1024], Bb + (size_t)i * 8 * ldb + koff);
    }
    const char* lA = lds[c];
    const char* lB = lds[c] + 16384;
#pragma unroll
    for (int kk = 0; kk < 64; kk += 32) {
      bf16x8 af[4], bf[2];
#pragma unroll
      for (int m = 0; m < 4; ++m)
        af[m] = *reinterpret_cast<const bf16x8*>(&lA[swz128(wm + m * 16 + lrow, (kk + lko) * 2)]);
#pragma unroll
      for (int n = 0; n < 2; ++n)
        bf[n] = *reinterpret_cast<const bf16x8*>(&lB[swz128(wn + n * 16 + lrow, (kk + lko) * 2)]);
      __builtin_amdgcn_s_setprio(1);
#pragma unroll
      for (int m = 0; m < 4; ++m)
#pragma unroll
        for (int n = 0; n < 2; ++n)
          acc[m][n] = __builtin_amdgcn_mfma_f32_16x16x32_bf16(af[m], bf[n], acc[m][n], 0, 0, 0);
      __builtin_amdgcn_s_setprio(0);
    }
    barrier_vm0();
  }

#pragma unroll
  for (int m = 0; m < 4; ++m)
#pragma unroll
    for (int n = 0; n < 2; ++n) {
      const int col = n0 + wn + n * 16 + lrow;
      const float bv = bias[col];
#pragma unroll
      for (int r = 0; r < 4; ++r) {
        const int row = m0 + wm + m * 16 + rbase + r;
        out[(size_t)row * D_MODEL + col] = acc[m][n][r] + bv;
      }
    }
}

// ---------------- fused ReLU attention (r6/r10-proven: counted-vmcnt barriers) ----------------
__global__ __launch_bounds__(512)
void attn_v2(const __hip_bfloat16* __restrict__ Qh,   // [bh][s][hd]
             const __hip_bfloat16* __restrict__ Kh,   // [bh][s][hd]
             const __hip_bfloat16* __restrict__ Vt,   // [bh][hd][s]
             float* __restrict__ attn,                // [bh][q][k]
             __hip_bfloat16* __restrict__ ctx) {      // [b][s][h*128+hd]
  __shared__ char ldsK[2][KVBLK * 256];
  __shared__ char ldsV[2][HDIM * 128];
  __shared__ char ldsP[128 * 128];

  const int tid = threadIdx.x, lane = tid & 63, wid = tid >> 6;
  const int lrow = lane & 15, lko = (lane >> 4) * 8, rbase = (lane >> 4) * 4;
  const int wqq = (wid >> 1) * 32;
  const int wqk = (wid & 1) * 32;
  const int whd = (wid & 1) * 64;

  const int raw = blockIdx.x;
  const int xcd = raw & 7, slot = raw >> 3;
  const int bh = xcd * 2 + (slot >> 4);
  const int q0 = (slot & 15) * 128;

  const char* Kg = (const char*)Kh + (size_t)bh * SEQ * HDIM * 2;
  const char* Vg = (const char*)Vt + (size_t)bh * HDIM * SEQ * 2;
  const __hip_bfloat16* Qg = Qh + ((size_t)bh * SEQ + q0) * HDIM;
  float* attnb = attn + ((size_t)bh * SEQ + q0) * SEQ;

  const int krl = lane >> 4;
  const int kcb = (lane & 15) * 16;
  const int vrl = lane >> 3;
  const int vsc = ((lane & 7) * 16) ^ (vrl << 4);

#pragma unroll
  for (int j = 0; j < 2; ++j) {
    const int rr = wid * 8 + j * 4 + krl;
    gload16((char*)ldsK[0] + (wid * 8 + j * 4) * 256,
            Kg + (size_t)rr * 256 + (kcb ^ ((rr & 7) << 4)));
    const int rv = wid * 16 + j * 8 + vrl;
    gload16((char*)ldsV[0] + (wid * 16 + j * 8) * 128,
            Vg + (size_t)rv * (SEQ * 2) + vsc);
  }

  bf16x8 qf[2][4];
#pragma unroll
  for (int m = 0; m < 2; ++m)
#pragma unroll
    for (int kk = 0; kk < 4; ++kk)
      qf[m][kk] = *reinterpret_cast<const bf16x8*>(
          Qg + (size_t)(wqq + m * 16 + lrow) * HDIM + kk * 32 + lko);

  f32x4 cacc[2][4];
  const f32x4 fz = {0.f, 0.f, 0.f, 0.f};
#pragma unroll
  for (int m = 0; m < 2; ++m)
#pragma unroll
    for (int n = 0; n < 4; ++n) cacc[m][n] = fz;

  const float scale = 0.08838834764831845f;  // 1/sqrt(128)
  __syncthreads();

  for (int t = 0; t < NT; ++t) {
    const int b = t & 1;
    if (t + 1 < NT) {
#pragma unroll
      for (int j = 0; j < 2; ++j) {
        const int rr = wid * 8 + j * 4 + krl;
        gload16((char*)ldsK[b ^ 1] + (wid * 8 + j * 4) * 256,
                Kg + (size_t)((t + 1) * KVBLK + rr) * 256 + (kcb ^ ((rr & 7) << 4)));
        const int rv = wid * 16 + j * 8 + vrl;
        gload16((char*)ldsV[b ^ 1] + (wid * 16 + j * 8) * 128,
                Vg + (size_t)rv * (SEQ * 2) + (t + 1) * 128 + vsc);
      }
    }

    f32x4 sacc[2][2];
#pragma unroll
    for (int m = 0; m < 2; ++m)
#pragma unroll
      for (int n = 0; n < 2; ++n) sacc[m][n] = fz;
    __builtin_amdgcn_s_setprio(1);
#pragma unroll
    for (int kk = 0; kk < 4; ++kk) {
      bf16x8 kf[2];
#pragma unroll
      for (int n = 0; n < 2; ++n)
        kf[n] = *reinterpret_cast<const bf16x8*>(
            &ldsK[b][swz256(wqk + n * 16 + lrow, (kk * 32 + lko) * 2)]);
#pragma unroll
      for (int m = 0; m < 2; ++m)
#pragma unroll
        for (int n = 0; n < 2; ++n)
          sacc[m][n] = __builtin_amdgcn_mfma_f32_16x16x32_bf16(qf[m][kk], kf[n], sacc[m][n], 0, 0, 0);
    }
    __builtin_amdgcn_s_setprio(0);

#pragma unroll
    for (int m = 0; m < 2; ++m)
#pragma unroll
      for (int n = 0; n < 2; ++n)
#pragma unroll
        for (int r = 0; r < 4; ++r) {
          const int ql = wqq + m * 16 + rbase + r;
          const int kl = wqk + n * 16 + lrow;
          const float s = fmaxf(sacc[m][n][r] * scale, 0.f);
          attnb[(size_t)ql * SEQ + t * KVBLK + kl] = s;
          *reinterpret_cast<__hip_bfloat16*>(&ldsP[swz128(ql, kl * 2)]) = __float2bfloat16(s);
        }
    barrier_lgkm();

    __builtin_amdgcn_s_setprio(1);
#pragma unroll
    for (int kk = 0; kk < 2; ++kk) {
      bf16x8 pf[2], vf[4];
#pragma unroll
      for (int m = 0; m < 2; ++m)
        pf[m] = *reinterpret_cast<const bf16x8*>(
            &ldsP[swz128(wqq + m * 16 + lrow, (kk * 32 + lko) * 2)]);
#pragma unroll
      for (int n = 0; n < 4; ++n)
        vf[n] = *reinterpret_cast<const bf16x8*>(
            &ldsV[b][swz128(whd + n * 16 + lrow, (kk * 32 + lko) * 2)]);
#pragma unroll
      for (int m = 0; m < 2; ++m)
#pragma unroll
        for (int n = 0; n < 4; ++n)
          cacc[m][n] = __builtin_amdgcn_mfma_f32_16x16x32_bf16(pf[m], vf[n], cacc[m][n], 0, 0, 0);
    }
    __builtin_amdgcn_s_setprio(0);
    barrier_vm16();
  }

  const int bb = bh >> 3, h = bh & 7;
#pragma unroll
  for (int m = 0; m < 2; ++m)
#pragma unroll
    for (int n = 0; n < 4; ++n)
#pragma unroll
      for (int r = 0; r < 4; ++r) {
        const int srow = q0 + wqq + m * 16 + rbase + r;
        const int hd = whd + n * 16 + lrow;
        ctx[((size_t)(bb * SEQ + srow)) * D_MODEL + h * HDIM + hd] =
            __float2bfloat16(cacc[m][n][r]);
      }
}

extern "C" void kernel_launch(void* const* d_in, const int* in_sizes, int n_in,
                              void* d_out, int out_size, void* d_ws, size_t ws_size,
                              hipStream_t stream) {
  const float* q  = (const float*)d_in[0];
  const float* k  = (const float*)d_in[1];
  const float* v  = (const float*)d_in[2];
  const float* Wq = (const float*)d_in[3];
  const float* bq = (const float*)d_in[4];
  const float* Wk = (const float*)d_in[5];
  const float* bk = (const float*)d_in[6];
  const float* Wv = (const float*)d_in[7];
  const float* bv = (const float*)d_in[8];
  const float* Wo = (const float*)d_in[9];
  const float* bo = (const float*)d_in[10];

  char* ws = (char*)d_ws;
  const size_t NE = (size_t)MTOT * D_MODEL;     // 4194304
  const size_t WE = (size_t)D_MODEL * D_MODEL;  // 1048576
  __hip_bfloat16* qb  = (__hip_bfloat16*)ws;
  __hip_bfloat16* kb  = qb + NE;
  __hip_bfloat16* vb  = kb + NE;
  __hip_bfloat16* Wqt = vb + NE;
  __hip_bfloat16* Wkt = Wqt + WE;
  __hip_bfloat16* Wvt = Wkt + WE;
  __hip_bfloat16* Wot = Wvt + WE;
  __hip_bfloat16* Qh  = Wot + WE;
  __hip_bfloat16* Kh  = Qh + NE;
  __hip_bfloat16* Vt  = Kh + NE;
  __hip_bfloat16* ctx = Vt + NE;

  prep<<<10240, 256, 0, stream>>>(q, k, v, qb, Wq, Wk, Wv, Wo, Wqt, Wkt, Wvt, Wot);

  GemmArgs gq{qb, Wqt, bq, Qh, 0};
  GemmArgs gk{kb, Wkt, bk, Kh, 0};
  GemmArgs gv{vb, Wvt, bv, Vt, 1};
  gemm_gl<<<dim3(32, 8, 3), 256, 0, stream>>>(gq, gk, gv, D_MODEL);

  float* outp  = (float*)d_out;
  float* attnp = outp + NE;
  attn_v2<<<256, 512, 0, stream>>>(Qh, Kh, Vt, attnp, ctx);

  gemm_out<<<dim3(32, 16), 256, 0, stream>>>(ctx, Wot, bo, (float*)d_out, D_MODEL);
}

// Round 13
// 147.600 us; speedup vs baseline: 1.0401x; 1.0401x over previous
//
#include <hip/hip_runtime.h>
#include <hip/hip_bf16.h>
#include <stdint.h>

#define D_MODEL 1024
#define NHEAD 8
#define HDIM 128
#define BATCH 2
#define SEQ 2048
#define MTOT (BATCH*SEQ)   // 4096
#define KVBLK 64
#define NT (SEQ/KVBLK)     // 32

typedef __attribute__((ext_vector_type(4))) float f32x4;
typedef __attribute__((ext_vector_type(8))) short bf16x8;

// XOR swizzle: LDS(row, c) holds element (row, c ^ ((row&7)<<4)). Involution,
// used identically on the pre-swizzled global source and the ds_read side (G21).
__device__ __forceinline__ uint32_t swz128(uint32_t row, uint32_t cb) {
  return row * 128u + (cb ^ ((row & 7u) << 4));
}
__device__ __forceinline__ uint32_t swz256(uint32_t row, uint32_t cb) {
  return row * 256u + (cb ^ ((row & 7u) << 4));
}

// async global->LDS, 16B per lane
__device__ __forceinline__ void gload16(void* lds, const void* g) {
  __builtin_amdgcn_global_load_lds(
      reinterpret_cast<const __attribute__((address_space(1))) uint32_t*>(
          reinterpret_cast<uintptr_t>(g)),
      reinterpret_cast<__attribute__((address_space(3))) uint32_t*>(
          (uint32_t)reinterpret_cast<uintptr_t>(lds)),
      16, 0, 0);
}

// Counted barriers (T4).
__device__ __forceinline__ void barrier_lgkm() {
  asm volatile("s_waitcnt lgkmcnt(0)\n\ts_barrier" ::: "memory");
}
__device__ __forceinline__ void barrier_vm16() {
  asm volatile("s_waitcnt vmcnt(16) lgkmcnt(0)\n\ts_barrier" ::: "memory");
}
__device__ __forceinline__ void barrier_vm0() {
  asm volatile("s_waitcnt vmcnt(0) lgkmcnt(0)\n\ts_barrier" ::: "memory");
}

// ---------------- prep: cast q/k/v fp32->bf16 (blocks [0,6144)) AND
// transpose+cast 4 weights (blocks [6144,10240)), one launch ----------------
__global__ __launch_bounds__(256)
void prep(const float* __restrict__ q, const float* __restrict__ k,
          const float* __restrict__ v, __hip_bfloat16* __restrict__ qkv_out,
          const float* __restrict__ w0, const float* __restrict__ w1,
          const float* __restrict__ w2, const float* __restrict__ w3,
          __hip_bfloat16* __restrict__ t0, __hip_bfloat16* __restrict__ t1,
          __hip_bfloat16* __restrict__ t2, __hip_bfloat16* __restrict__ t3) {
  const int bid = blockIdx.x;
  const int tid = threadIdx.x;
  if (bid < 6144) {
    const int which = bid >> 11;          // 0..2
    const int blk = bid & 2047;
    const float* src = which == 0 ? q : (which == 1 ? k : v);
    const size_t NE = (size_t)MTOT * D_MODEL;
    size_t i = ((size_t)blk * 256 + tid) * 8;
    float4 a = *reinterpret_cast<const float4*>(src + i);
    float4 b = *reinterpret_cast<const float4*>(src + i + 4);
    __hip_bfloat16 o[8] = {__float2bfloat16(a.x), __float2bfloat16(a.y),
                           __float2bfloat16(a.z), __float2bfloat16(a.w),
                           __float2bfloat16(b.x), __float2bfloat16(b.y),
                           __float2bfloat16(b.z), __float2bfloat16(b.w)};
    *reinterpret_cast<uint4*>(qkv_out + which * NE + i) =
        *reinterpret_cast<const uint4*>(o);
  } else {
    const int rb = bid - 6144;
    const int z = rb >> 10;               // 0..3
    const int rem = rb & 1023;
    const float* W = z == 0 ? w0 : z == 1 ? w1 : z == 2 ? w2 : w3;
    __hip_bfloat16* Wt = z == 0 ? t0 : z == 1 ? t1 : z == 2 ? t2 : t3;
    __shared__ float t[32][33];
    const int x = tid & 31, y = tid >> 5;  // 32 x 8
    const int n0 = (rem & 31) * 32, k0 = (rem >> 5) * 32;
#pragma unroll
    for (int i = 0; i < 4; ++i)
      t[y + i * 8][x] = W[(size_t)(k0 + y + i * 8) * D_MODEL + n0 + x];
    __syncthreads();
#pragma unroll
    for (int i = 0; i < 4; ++i)
      Wt[(size_t)(n0 + y + i * 8) * D_MODEL + k0 + x] = __float2bfloat16(t[x][y + i * 8]);
  }
}

struct GemmArgs {
  const __hip_bfloat16* A;   // [M][K]
  const __hip_bfloat16* B;   // [N][K]  (W^T)
  const float* bias;         // [N]
  void* out;
  int mode;  // 0: bf16 [bh][s][hd]; 1: bf16 [bh][hd][s] (LDS-transposed store); 2: fp32 [row][col]
};

// ---------------- 128x128 bf16 GEMM, double-buffered prefetch K-loop (r8-proven) ----------------
// mode-1 epilogue: stage 128(hd)x128(s) bf16 tile in LDS (swz256), then store
// 256B-contiguous rows -> kills the 4KB-stride 8B-chunk scatter (8x write amp).
__global__ __launch_bounds__(256)
void gemm_gl(GemmArgs g0, GemmArgs g1, GemmArgs g2, int K) {
  __shared__ char lds[2][32768];   // per buf: A 16KB | B 16KB
  GemmArgs ga = blockIdx.z == 0 ? g0 : (blockIdx.z == 1 ? g1 : g2);

  const int tid = threadIdx.x, lane = tid & 63, wid = tid >> 6;
  const int lrow = lane & 15, lko = (lane >> 4) * 8, rbase = (lane >> 4) * 4;
  const int m0 = blockIdx.x * 128, n0 = blockIdx.y * 128;
  const size_t ldb = (size_t)K * 2;

  const int srow = lane >> 3;                       // row within 8-row call
  const int sca = ((lane & 7) * 16) ^ (srow << 4);  // pre-swizzled source col
  const char* Ab = (const char*)ga.A + (size_t)(m0 + wid * 32 + srow) * ldb + sca;
  const char* Bb = (const char*)ga.B + (size_t)(n0 + wid * 32 + srow) * ldb + sca;
  const int sdst = wid * 32 * 128;                  // wave's LDS row base (bytes)

  f32x4 acc[4][4];
  const f32x4 fz = {0.f, 0.f, 0.f, 0.f};
#pragma unroll
  for (int m = 0; m < 4; ++m)
#pragma unroll
    for (int n = 0; n < 4; ++n) acc[m][n] = fz;

  const int wm = (wid >> 1) * 64, wn = (wid & 1) * 64;
  const int NKT = K >> 6;

  // prologue: stage tile 0 into buf 0
#pragma unroll
  for (int i = 0; i < 4; ++i) {
    gload16(&lds[0][sdst + i * 8 * 128], Ab + (size_t)i * 8 * ldb);
    gload16(&lds[0][16384 + sdst + i * 8 * 128], Bb + (size_t)i * 8 * ldb);
  }
  barrier_vm0();   // tile 0 ready

  for (int kt = 0; kt < NKT; ++kt) {
    const int c = kt & 1;
    if (kt + 1 < NKT) {  // prefetch next tile into other buffer
      const size_t koff = (size_t)(kt + 1) * 128;
#pragma unroll
      for (int i = 0; i < 4; ++i) {
        gload16(&lds[c ^ 1][sdst + i * 8 * 128], Ab + (size_t)i * 8 * ldb + koff);
        gload16(&lds[c ^ 1][16384 + sdst + i * 8 * 128], Bb + (size_t)i * 8 * ldb + koff);
      }
    }
    const char* lA = lds[c];
    const char* lB = lds[c] + 16384;
#pragma unroll
    for (int kk = 0; kk < 64; kk += 32) {
      bf16x8 af[4], bf[4];
#pragma unroll
      for (int m = 0; m < 4; ++m)
        af[m] = *reinterpret_cast<const bf16x8*>(&lA[swz128(wm + m * 16 + lrow, (kk + lko) * 2)]);
#pragma unroll
      for (int n = 0; n < 4; ++n)
        bf[n] = *reinterpret_cast<const bf16x8*>(&lB[swz128(wn + n * 16 + lrow, (kk + lko) * 2)]);
      __builtin_amdgcn_s_setprio(1);
#pragma unroll
      for (int m = 0; m < 4; ++m)
#pragma unroll
        for (int n = 0; n < 4; ++n)
          acc[m][n] = __builtin_amdgcn_mfma_f32_16x16x32_bf16(af[m], bf[n], acc[m][n], 0, 0, 0);
      __builtin_amdgcn_s_setprio(0);
    }
    barrier_vm0();  // prefetch complete + all ds_reads retired -> bufs swap safely
  }

  if (ga.mode == 2) {
#pragma unroll
    for (int m = 0; m < 4; ++m)
#pragma unroll
      for (int n = 0; n < 4; ++n) {
        const int col = n0 + wn + n * 16 + lrow;
        const float bv = ga.bias[col];
#pragma unroll
        for (int r = 0; r < 4; ++r) {
          const int row = m0 + wm + m * 16 + rbase + r;
          reinterpret_cast<float*>(ga.out)[(size_t)row * D_MODEL + col] = acc[m][n][r] + bv;
        }
      }
  } else if (ga.mode == 0) {
#pragma unroll
    for (int m = 0; m < 4; ++m)
#pragma unroll
      for (int n = 0; n < 4; ++n) {
        const int col = n0 + wn + n * 16 + lrow;
        const float bv = ga.bias[col];
        const int h = col >> 7, hd = col & 127;
#pragma unroll
        for (int r = 0; r < 4; ++r) {
          const int row = m0 + wm + m * 16 + rbase + r;
          const int b = row >> 11, s = row & 2047;
          reinterpret_cast<__hip_bfloat16*>(ga.out)[((size_t)(b * NHEAD + h) * SEQ + s) * HDIM + hd] =
              __float2bfloat16(acc[m][n][r] + bv);
        }
      }
  } else {
    // mode 1: Vt[bh][hd][s]. Direct store would be 8B chunks at 4KB stride
    // (8x write amplification). Instead: LDS transpose (K-loop LDS is free
    // after the final barrier_vm0) -> coalesced 256B-row stores.
    char* T = lds[0];  // 32KB: [hd 128][s 128] bf16, swz256 rows
#pragma unroll
    for (int m = 0; m < 4; ++m)
#pragma unroll
      for (int n = 0; n < 4; ++n) {
        const int hdl = wn + n * 16 + lrow;
        const float bv = ga.bias[n0 + hdl];
#pragma unroll
        for (int r = 0; r < 4; ++r) {
          const int sl = wm + m * 16 + rbase + r;
          *reinterpret_cast<__hip_bfloat16*>(&T[swz256(hdl, sl * 2)]) =
              __float2bfloat16(acc[m][n][r] + bv);
        }
      }
    __syncthreads();
    // store 128 rows x 256B: 16 lanes x 16B per row, 16 rows per pass, 8 passes
    const int b = m0 >> 11, h = n0 >> 7;   // block spans one b and one head
    char* vtb = (char*)ga.out +
                (((size_t)(b * NHEAD + h) * HDIM) * SEQ + (m0 & 2047)) * 2;
    const int lr16 = tid >> 4;             // row within pass (0..15)
    const int lc16 = (tid & 15) * 16;      // byte col within 256B row
#pragma unroll
    for (int p = 0; p < 8; ++p) {
      const int hdl = p * 16 + lr16;
      uint4 vv = *reinterpret_cast<const uint4*>(&T[swz256(hdl, lc16)]);
      *reinterpret_cast<uint4*>(vtb + (size_t)hdl * (SEQ * 2) + lc16) = vv;
    }
  }
}

// ---------------- fused ReLU attention (r6/r10-proven: counted-vmcnt barriers) ----------------
__global__ __launch_bounds__(512)
void attn_v2(const __hip_bfloat16* __restrict__ Qh,   // [bh][s][hd]
             const __hip_bfloat16* __restrict__ Kh,   // [bh][s][hd]
             const __hip_bfloat16* __restrict__ Vt,   // [bh][hd][s]
             float* __restrict__ attn,                // [bh][q][k]
             __hip_bfloat16* __restrict__ ctx) {      // [b][s][h*128+hd]
  __shared__ char ldsK[2][KVBLK * 256];
  __shared__ char ldsV[2][HDIM * 128];
  __shared__ char ldsP[128 * 128];

  const int tid = threadIdx.x, lane = tid & 63, wid = tid >> 6;
  const int lrow = lane & 15, lko = (lane >> 4) * 8, rbase = (lane >> 4) * 4;
  const int wqq = (wid >> 1) * 32;
  const int wqk = (wid & 1) * 32;
  const int whd = (wid & 1) * 64;

  const int raw = blockIdx.x;
  const int xcd = raw & 7, slot = raw >> 3;
  const int bh = xcd * 2 + (slot >> 4);
  const int q0 = (slot & 15) * 128;

  const char* Kg = (const char*)Kh + (size_t)bh * SEQ * HDIM * 2;
  const char* Vg = (const char*)Vt + (size_t)bh * HDIM * SEQ * 2;
  const __hip_bfloat16* Qg = Qh + ((size_t)bh * SEQ + q0) * HDIM;
  float* attnb = attn + ((size_t)bh * SEQ + q0) * SEQ;

  const int krl = lane >> 4;
  const int kcb = (lane & 15) * 16;
  const int vrl = lane >> 3;
  const int vsc = ((lane & 7) * 16) ^ (vrl << 4);

#pragma unroll
  for (int j = 0; j < 2; ++j) {
    const int rr = wid * 8 + j * 4 + krl;
    gload16((char*)ldsK[0] + (wid * 8 + j * 4) * 256,
            Kg + (size_t)rr * 256 + (kcb ^ ((rr & 7) << 4)));
    const int rv = wid * 16 + j * 8 + vrl;
    gload16((char*)ldsV[0] + (wid * 16 + j * 8) * 128,
            Vg + (size_t)rv * (SEQ * 2) + vsc);
  }

  bf16x8 qf[2][4];
#pragma unroll
  for (int m = 0; m < 2; ++m)
#pragma unroll
    for (int kk = 0; kk < 4; ++kk)
      qf[m][kk] = *reinterpret_cast<const bf16x8*>(
          Qg + (size_t)(wqq + m * 16 + lrow) * HDIM + kk * 32 + lko);

  f32x4 cacc[2][4];
  const f32x4 fz = {0.f, 0.f, 0.f, 0.f};
#pragma unroll
  for (int m = 0; m < 2; ++m)
#pragma unroll
    for (int n = 0; n < 4; ++n) cacc[m][n] = fz;

  const float scale = 0.08838834764831845f;  // 1/sqrt(128)
  __syncthreads();

  for (int t = 0; t < NT; ++t) {
    const int b = t & 1;
    if (t + 1 < NT) {
#pragma unroll
      for (int j = 0; j < 2; ++j) {
        const int rr = wid * 8 + j * 4 + krl;
        gload16((char*)ldsK[b ^ 1] + (wid * 8 + j * 4) * 256,
                Kg + (size_t)((t + 1) * KVBLK + rr) * 256 + (kcb ^ ((rr & 7) << 4)));
        const int rv = wid * 16 + j * 8 + vrl;
        gload16((char*)ldsV[b ^ 1] + (wid * 16 + j * 8) * 128,
                Vg + (size_t)rv * (SEQ * 2) + (t + 1) * 128 + vsc);
      }
    }

    f32x4 sacc[2][2];
#pragma unroll
    for (int m = 0; m < 2; ++m)
#pragma unroll
      for (int n = 0; n < 2; ++n) sacc[m][n] = fz;
    __builtin_amdgcn_s_setprio(1);
#pragma unroll
    for (int kk = 0; kk < 4; ++kk) {
      bf16x8 kf[2];
#pragma unroll
      for (int n = 0; n < 2; ++n)
        kf[n] = *reinterpret_cast<const bf16x8*>(
            &ldsK[b][swz256(wqk + n * 16 + lrow, (kk * 32 + lko) * 2)]);
#pragma unroll
      for (int m = 0; m < 2; ++m)
#pragma unroll
        for (int n = 0; n < 2; ++n)
          sacc[m][n] = __builtin_amdgcn_mfma_f32_16x16x32_bf16(qf[m][kk], kf[n], sacc[m][n], 0, 0, 0);
    }
    __builtin_amdgcn_s_setprio(0);

#pragma unroll
    for (int m = 0; m < 2; ++m)
#pragma unroll
      for (int n = 0; n < 2; ++n)
#pragma unroll
        for (int r = 0; r < 4; ++r) {
          const int ql = wqq + m * 16 + rbase + r;
          const int kl = wqk + n * 16 + lrow;
          const float s = fmaxf(sacc[m][n][r] * scale, 0.f);
          attnb[(size_t)ql * SEQ + t * KVBLK + kl] = s;
          *reinterpret_cast<__hip_bfloat16*>(&ldsP[swz128(ql, kl * 2)]) = __float2bfloat16(s);
        }
    barrier_lgkm();

    __builtin_amdgcn_s_setprio(1);
#pragma unroll
    for (int kk = 0; kk < 2; ++kk) {
      bf16x8 pf[2], vf[4];
#pragma unroll
      for (int m = 0; m < 2; ++m)
        pf[m] = *reinterpret_cast<const bf16x8*>(
            &ldsP[swz128(wqq + m * 16 + lrow, (kk * 32 + lko) * 2)]);
#pragma unroll
      for (int n = 0; n < 4; ++n)
        vf[n] = *reinterpret_cast<const bf16x8*>(
            &ldsV[b][swz128(whd + n * 16 + lrow, (kk * 32 + lko) * 2)]);
#pragma unroll
      for (int m = 0; m < 2; ++m)
#pragma unroll
        for (int n = 0; n < 4; ++n)
          cacc[m][n] = __builtin_amdgcn_mfma_f32_16x16x32_bf16(pf[m], vf[n], cacc[m][n], 0, 0, 0);
    }
    __builtin_amdgcn_s_setprio(0);
    barrier_vm16();
  }

  const int bb = bh >> 3, h = bh & 7;
#pragma unroll
  for (int m = 0; m < 2; ++m)
#pragma unroll
    for (int n = 0; n < 4; ++n)
#pragma unroll
      for (int r = 0; r < 4; ++r) {
        const int srow = q0 + wqq + m * 16 + rbase + r;
        const int hd = whd + n * 16 + lrow;
        ctx[((size_t)(bb * SEQ + srow)) * D_MODEL + h * HDIM + hd] =
            __float2bfloat16(cacc[m][n][r]);
      }
}

extern "C" void kernel_launch(void* const* d_in, const int* in_sizes, int n_in,
                              void* d_out, int out_size, void* d_ws, size_t ws_size,
                              hipStream_t stream) {
  const float* q  = (const float*)d_in[0];
  const float* k  = (const float*)d_in[1];
  const float* v  = (const float*)d_in[2];
  const float* Wq = (const float*)d_in[3];
  const float* bq = (const float*)d_in[4];
  const float* Wk = (const float*)d_in[5];
  const float* bk = (const float*)d_in[6];
  const float* Wv = (const float*)d_in[7];
  const float* bv = (const float*)d_in[8];
  const float* Wo = (const float*)d_in[9];
  const float* bo = (const float*)d_in[10];

  char* ws = (char*)d_ws;
  const size_t NE = (size_t)MTOT * D_MODEL;     // 4194304
  const size_t WE = (size_t)D_MODEL * D_MODEL;  // 1048576
  __hip_bfloat16* qb  = (__hip_bfloat16*)ws;
  __hip_bfloat16* kb  = qb + NE;
  __hip_bfloat16* vb  = kb + NE;
  __hip_bfloat16* Wqt = vb + NE;
  __hip_bfloat16* Wkt = Wqt + WE;
  __hip_bfloat16* Wvt = Wkt + WE;
  __hip_bfloat16* Wot = Wvt + WE;
  __hip_bfloat16* Qh  = Wot + WE;
  __hip_bfloat16* Kh  = Qh + NE;
  __hip_bfloat16* Vt  = Kh + NE;
  __hip_bfloat16* ctx = Vt + NE;

  prep<<<10240, 256, 0, stream>>>(q, k, v, qb, Wq, Wk, Wv, Wo, Wqt, Wkt, Wvt, Wot);

  GemmArgs gq{qb, Wqt, bq, Qh, 0};
  GemmArgs gk{kb, Wkt, bk, Kh, 0};
  GemmArgs gv{vb, Wvt, bv, Vt, 1};
  gemm_gl<<<dim3(32, 8, 3), 256, 0, stream>>>(gq, gk, gv, D_MODEL);

  float* outp  = (float*)d_out;
  float* attnp = outp + NE;
  attn_v2<<<256, 512, 0, stream>>>(Qh, Kh, Vt, attnp, ctx);

  GemmArgs go{ctx, Wot, bo, d_out, 2};
  gemm_gl<<<dim3(32, 8, 1), 256, 0, stream>>>(go, go, go, D_MODEL);
}

// Round 14
// 144.079 us; speedup vs baseline: 1.0655x; 1.0244x over previous
//
#include <hip/hip_runtime.h>
#include <hip/hip_bf16.h>
#include <stdint.h>

#define D_MODEL 1024
#define NHEAD 8
#define HDIM 128
#define BATCH 2
#define SEQ 2048
#define MTOT (BATCH*SEQ)   // 4096
#define KVBLK 128
#define NT (SEQ/KVBLK)     // 16

typedef __attribute__((ext_vector_type(4))) float f32x4;
typedef __attribute__((ext_vector_type(8))) short bf16x8;

// XOR swizzle: LDS(row, c) holds element (row, c ^ ((row&7)<<4)). Involution,
// used identically on the pre-swizzled global source and the ds_read side (G21).
__device__ __forceinline__ uint32_t swz128(uint32_t row, uint32_t cb) {
  return row * 128u + (cb ^ ((row & 7u) << 4));
}
__device__ __forceinline__ uint32_t swz256(uint32_t row, uint32_t cb) {
  return row * 256u + (cb ^ ((row & 7u) << 4));
}

// async global->LDS, 16B per lane
__device__ __forceinline__ void gload16(void* lds, const void* g) {
  __builtin_amdgcn_global_load_lds(
      reinterpret_cast<const __attribute__((address_space(1))) uint32_t*>(
          reinterpret_cast<uintptr_t>(g)),
      reinterpret_cast<__attribute__((address_space(3))) uint32_t*>(
          (uint32_t)reinterpret_cast<uintptr_t>(lds)),
      16, 0, 0);
}

// Counted barriers (T4).
__device__ __forceinline__ void barrier_lgkm() {
  asm volatile("s_waitcnt lgkmcnt(0)\n\ts_barrier" ::: "memory");
}
// mid barrier: retire carry stores (32) + this iter's 8 gloads; keep <=32 stores in flight
__device__ __forceinline__ void barrier_vm32() {
  asm volatile("s_waitcnt vmcnt(32) lgkmcnt(0)\n\ts_barrier" ::: "memory");
}
__device__ __forceinline__ void barrier_vm0() {
  asm volatile("s_waitcnt vmcnt(0) lgkmcnt(0)\n\ts_barrier" ::: "memory");
}

// ---------------- prep: cast q/k/v fp32->bf16 (blocks [0,6144)) AND
// transpose+cast 4 weights (blocks [6144,10240)), one launch ----------------
__global__ __launch_bounds__(256)
void prep(const float* __restrict__ q, const float* __restrict__ k,
          const float* __restrict__ v, __hip_bfloat16* __restrict__ qkv_out,
          const float* __restrict__ w0, const float* __restrict__ w1,
          const float* __restrict__ w2, const float* __restrict__ w3,
          __hip_bfloat16* __restrict__ t0, __hip_bfloat16* __restrict__ t1,
          __hip_bfloat16* __restrict__ t2, __hip_bfloat16* __restrict__ t3) {
  const int bid = blockIdx.x;
  const int tid = threadIdx.x;
  if (bid < 6144) {
    const int which = bid >> 11;          // 0..2
    const int blk = bid & 2047;
    const float* src = which == 0 ? q : (which == 1 ? k : v);
    const size_t NE = (size_t)MTOT * D_MODEL;
    size_t i = ((size_t)blk * 256 + tid) * 8;
    float4 a = *reinterpret_cast<const float4*>(src + i);
    float4 b = *reinterpret_cast<const float4*>(src + i + 4);
    __hip_bfloat16 o[8] = {__float2bfloat16(a.x), __float2bfloat16(a.y),
                           __float2bfloat16(a.z), __float2bfloat16(a.w),
                           __float2bfloat16(b.x), __float2bfloat16(b.y),
                           __float2bfloat16(b.z), __float2bfloat16(b.w)};
    *reinterpret_cast<uint4*>(qkv_out + which * NE + i) =
        *reinterpret_cast<const uint4*>(o);
  } else {
    const int rb = bid - 6144;
    const int z = rb >> 10;               // 0..3
    const int rem = rb & 1023;
    const float* W = z == 0 ? w0 : z == 1 ? w1 : z == 2 ? w2 : w3;
    __hip_bfloat16* Wt = z == 0 ? t0 : z == 1 ? t1 : z == 2 ? t2 : t3;
    __shared__ float t[32][33];
    const int x = tid & 31, y = tid >> 5;  // 32 x 8
    const int n0 = (rem & 31) * 32, k0 = (rem >> 5) * 32;
#pragma unroll
    for (int i = 0; i < 4; ++i)
      t[y + i * 8][x] = W[(size_t)(k0 + y + i * 8) * D_MODEL + n0 + x];
    __syncthreads();
#pragma unroll
    for (int i = 0; i < 4; ++i)
      Wt[(size_t)(n0 + y + i * 8) * D_MODEL + k0 + x] = __float2bfloat16(t[x][y + i * 8]);
  }
}

struct GemmArgs {
  const __hip_bfloat16* A;   // [M][K]
  const __hip_bfloat16* B;   // [N][K]  (W^T)
  const float* bias;         // [N]
  void* out;
  int mode;  // 0: bf16 [bh][s][hd]; 1: bf16 [bh][hd][s] (LDS-transposed store); 2: fp32 [row][col]
};

// ---------------- 128x128 bf16 GEMM, double-buffered prefetch K-loop (r8-proven) ----------------
// mode-1 epilogue: LDS-transpose then coalesced 256B-row stores (r13-proven).
__global__ __launch_bounds__(256)
void gemm_gl(GemmArgs g0, GemmArgs g1, GemmArgs g2, int K) {
  __shared__ char lds[2][32768];   // per buf: A 16KB | B 16KB
  GemmArgs ga = blockIdx.z == 0 ? g0 : (blockIdx.z == 1 ? g1 : g2);

  const int tid = threadIdx.x, lane = tid & 63, wid = tid >> 6;
  const int lrow = lane & 15, lko = (lane >> 4) * 8, rbase = (lane >> 4) * 4;
  const int m0 = blockIdx.x * 128, n0 = blockIdx.y * 128;
  const size_t ldb = (size_t)K * 2;

  const int srow = lane >> 3;                       // row within 8-row call
  const int sca = ((lane & 7) * 16) ^ (srow << 4);  // pre-swizzled source col
  const char* Ab = (const char*)ga.A + (size_t)(m0 + wid * 32 + srow) * ldb + sca;
  const char* Bb = (const char*)ga.B + (size_t)(n0 + wid * 32 + srow) * ldb + sca;
  const int sdst = wid * 32 * 128;                  // wave's LDS row base (bytes)

  f32x4 acc[4][4];
  const f32x4 fz = {0.f, 0.f, 0.f, 0.f};
#pragma unroll
  for (int m = 0; m < 4; ++m)
#pragma unroll
    for (int n = 0; n < 4; ++n) acc[m][n] = fz;

  const int wm = (wid >> 1) * 64, wn = (wid & 1) * 64;
  const int NKT = K >> 6;

  // prologue: stage tile 0 into buf 0
#pragma unroll
  for (int i = 0; i < 4; ++i) {
    gload16(&lds[0][sdst + i * 8 * 128], Ab + (size_t)i * 8 * ldb);
    gload16(&lds[0][16384 + sdst + i * 8 * 128], Bb + (size_t)i * 8 * ldb);
  }
  barrier_vm0();   // tile 0 ready

  for (int kt = 0; kt < NKT; ++kt) {
    const int c = kt & 1;
    if (kt + 1 < NKT) {  // prefetch next tile into other buffer
      const size_t koff = (size_t)(kt + 1) * 128;
#pragma unroll
      for (int i = 0; i < 4; ++i) {
        gload16(&lds[c ^ 1][sdst + i * 8 * 128], Ab + (size_t)i * 8 * ldb + koff);
        gload16(&lds[c ^ 1][16384 + sdst + i * 8 * 128], Bb + (size_t)i * 8 * ldb + koff);
      }
    }
    const char* lA = lds[c];
    const char* lB = lds[c] + 16384;
#pragma unroll
    for (int kk = 0; kk < 64; kk += 32) {
      bf16x8 af[4], bf[4];
#pragma unroll
      for (int m = 0; m < 4; ++m)
        af[m] = *reinterpret_cast<const bf16x8*>(&lA[swz128(wm + m * 16 + lrow, (kk + lko) * 2)]);
#pragma unroll
      for (int n = 0; n < 4; ++n)
        bf[n] = *reinterpret_cast<const bf16x8*>(&lB[swz128(wn + n * 16 + lrow, (kk + lko) * 2)]);
      __builtin_amdgcn_s_setprio(1);
#pragma unroll
      for (int m = 0; m < 4; ++m)
#pragma unroll
        for (int n = 0; n < 4; ++n)
          acc[m][n] = __builtin_amdgcn_mfma_f32_16x16x32_bf16(af[m], bf[n], acc[m][n], 0, 0, 0);
      __builtin_amdgcn_s_setprio(0);
    }
    barrier_vm0();  // prefetch complete + all ds_reads retired -> bufs swap safely
  }

  if (ga.mode == 2) {
#pragma unroll
    for (int m = 0; m < 4; ++m)
#pragma unroll
      for (int n = 0; n < 4; ++n) {
        const int col = n0 + wn + n * 16 + lrow;
        const float bv = ga.bias[col];
#pragma unroll
        for (int r = 0; r < 4; ++r) {
          const int row = m0 + wm + m * 16 + rbase + r;
          reinterpret_cast<float*>(ga.out)[(size_t)row * D_MODEL + col] = acc[m][n][r] + bv;
        }
      }
  } else if (ga.mode == 0) {
#pragma unroll
    for (int m = 0; m < 4; ++m)
#pragma unroll
      for (int n = 0; n < 4; ++n) {
        const int col = n0 + wn + n * 16 + lrow;
        const float bv = ga.bias[col];
        const int h = col >> 7, hd = col & 127;
#pragma unroll
        for (int r = 0; r < 4; ++r) {
          const int row = m0 + wm + m * 16 + rbase + r;
          const int b = row >> 11, s = row & 2047;
          reinterpret_cast<__hip_bfloat16*>(ga.out)[((size_t)(b * NHEAD + h) * SEQ + s) * HDIM + hd] =
              __float2bfloat16(acc[m][n][r] + bv);
        }
      }
  } else {
    // mode 1: Vt[bh][hd][s] via LDS transpose -> coalesced 256B-row stores.
    char* T = lds[0];  // 32KB: [hd 128][s 128] bf16, swz256 rows
#pragma unroll
    for (int m = 0; m < 4; ++m)
#pragma unroll
      for (int n = 0; n < 4; ++n) {
        const int hdl = wn + n * 16 + lrow;
        const float bv = ga.bias[n0 + hdl];
#pragma unroll
        for (int r = 0; r < 4; ++r) {
          const int sl = wm + m * 16 + rbase + r;
          *reinterpret_cast<__hip_bfloat16*>(&T[swz256(hdl, sl * 2)]) =
              __float2bfloat16(acc[m][n][r] + bv);
        }
      }
    __syncthreads();
    const int b = m0 >> 11, h = n0 >> 7;   // block spans one b and one head
    char* vtb = (char*)ga.out +
                (((size_t)(b * NHEAD + h) * HDIM) * SEQ + (m0 & 2047)) * 2;
    const int lr16 = tid >> 4;             // row within pass (0..15)
    const int lc16 = (tid & 15) * 16;      // byte col within 256B row
#pragma unroll
    for (int p = 0; p < 8; ++p) {
      const int hdl = p * 16 + lr16;
      uint4 vv = *reinterpret_cast<const uint4*>(&T[swz256(hdl, lc16)]);
      *reinterpret_cast<uint4*>(vtb + (size_t)hdl * (SEQ * 2) + lc16) = vv;
    }
  }
}

// ---------------- fused ReLU attention v6: KVBLK=128, half the barriers ----------------
// 8 waves; QK: wave = 32q x 64k (wqq 4 groups x wqk 2 halves), 32 MFMA/phase;
// PV: wave = 32q x 64hd over all 128 k, 32 MFMA/phase. LDS 128KB: K dbuf 2x32K,
// V single 32K, P 32K. Per iter: stage V_t + prefetch K_{t+1} (8 gloads/wave),
// QK, 32 stores, MID barrier vmcnt(32) (retires carry-stores + gloads; this
// iter's stores stay in flight), PV, END barrier lgkmcnt(0) only.
__global__ __launch_bounds__(512)
void attn_v6(const __hip_bfloat16* __restrict__ Qh,   // [bh][s][hd]
             const __hip_bfloat16* __restrict__ Kh,   // [bh][s][hd]
             const __hip_bfloat16* __restrict__ Vt,   // [bh][hd][s]
             float* __restrict__ attn,                // [bh][q][k]
             __hip_bfloat16* __restrict__ ctx) {      // [b][s][h*128+hd]
  __shared__ char ldsK[2][KVBLK * 256];   // 2 x 32KB, rows=key, 256B (128 hd)
  __shared__ char ldsV[HDIM * 256];       // 32KB, rows=hd, 256B (128 key)
  __shared__ char ldsP[128 * 256];        // 32KB, rows=q, 256B (128 key bf16)

  const int tid = threadIdx.x, lane = tid & 63, wid = tid >> 6;
  const int lrow = lane & 15, lko = (lane >> 4) * 8, rbase = (lane >> 4) * 4;
  const int wqq = (wid >> 1) * 32;   // q offset (4 groups)
  const int wqk = (wid & 1) * 64;    // key half in QK (2 groups of 64)
  const int whd = (wid & 1) * 64;    // hd half in PV

  const int raw = blockIdx.x;
  const int xcd = raw & 7, slot = raw >> 3;
  const int bh = xcd * 2 + (slot >> 4);
  const int q0 = (slot & 15) * 128;

  const char* Kg = (const char*)Kh + (size_t)bh * SEQ * HDIM * 2;
  const char* Vg = (const char*)Vt + (size_t)bh * HDIM * SEQ * 2;
  const __hip_bfloat16* Qg = Qh + ((size_t)bh * SEQ + q0) * HDIM;
  float* attnb = attn + ((size_t)bh * SEQ + q0) * SEQ;

  const int srl = lane >> 4;             // row within 4-row (1KB) gload call
  const int scb = (lane & 15) * 16;      // byte col within 256B row

  // prologue: stage K tile 0 (each wave: 16 rows, 4 calls)
#pragma unroll
  for (int j = 0; j < 4; ++j) {
    const int rr = wid * 16 + j * 4 + srl;
    gload16((char*)ldsK[0] + (wid * 16 + j * 4) * 256,
            Kg + (size_t)rr * 256 + (scb ^ ((rr & 7) << 4)));
  }

  // Q -> registers (reused all 16 tiles)
  bf16x8 qf[2][4];
#pragma unroll
  for (int m = 0; m < 2; ++m)
#pragma unroll
    for (int kk = 0; kk < 4; ++kk)
      qf[m][kk] = *reinterpret_cast<const bf16x8*>(
          Qg + (size_t)(wqq + m * 16 + lrow) * HDIM + kk * 32 + lko);

  f32x4 cacc[2][4];
  const f32x4 fz = {0.f, 0.f, 0.f, 0.f};
#pragma unroll
  for (int m = 0; m < 2; ++m)
#pragma unroll
    for (int n = 0; n < 4; ++n) cacc[m][n] = fz;

  const float scale = 0.08838834764831845f;  // 1/sqrt(128)
  __syncthreads();   // full drain: K0 + qf ready

  for (int t = 0; t < NT; ++t) {
    const int b = t & 1;
    // stage V_t (single buffer; prev PV ds_reads drained at prev END barrier)
#pragma unroll
    for (int j = 0; j < 4; ++j) {
      const int rv = wid * 16 + j * 4 + srl;
      gload16((char*)ldsV + (wid * 16 + j * 4) * 256,
              Vg + (size_t)rv * (SEQ * 2) + t * 256 + (scb ^ ((rv & 7) << 4)));
    }
    if (t + 1 < NT) {  // prefetch K tile t+1 into other buffer
#pragma unroll
      for (int j = 0; j < 4; ++j) {
        const int rr = wid * 16 + j * 4 + srl;
        gload16((char*)ldsK[b ^ 1] + (wid * 16 + j * 4) * 256,
                Kg + (size_t)((t + 1) * KVBLK + rr) * 256 + (scb ^ ((rr & 7) << 4)));
      }
    }

    // QK^T: S[128q x 128k]; wave = 32q x 64k (ldsK[b] ready per prev MID barrier)
    f32x4 sacc[2][4];
#pragma unroll
    for (int m = 0; m < 2; ++m)
#pragma unroll
      for (int n = 0; n < 4; ++n) sacc[m][n] = fz;
    __builtin_amdgcn_s_setprio(1);
#pragma unroll
    for (int kk = 0; kk < 4; ++kk) {
      bf16x8 kf[4];
#pragma unroll
      for (int n = 0; n < 4; ++n)
        kf[n] = *reinterpret_cast<const bf16x8*>(
            &ldsK[b][swz256(wqk + n * 16 + lrow, (kk * 32 + lko) * 2)]);
#pragma unroll
      for (int m = 0; m < 2; ++m)
#pragma unroll
        for (int n = 0; n < 4; ++n)
          sacc[m][n] = __builtin_amdgcn_mfma_f32_16x16x32_bf16(qf[m][kk], kf[n], sacc[m][n], 0, 0, 0);
    }
    __builtin_amdgcn_s_setprio(0);

    // scale + relu -> global fp32 attn (32 stores/wave, left in flight) + bf16 P
#pragma unroll
    for (int m = 0; m < 2; ++m)
#pragma unroll
      for (int n = 0; n < 4; ++n)
#pragma unroll
        for (int r = 0; r < 4; ++r) {
          const int ql = wqq + m * 16 + rbase + r;
          const int kl = wqk + n * 16 + lrow;
          const float s = fmaxf(sacc[m][n][r] * scale, 0.f);
          attnb[(size_t)ql * SEQ + t * KVBLK + kl] = s;
          *reinterpret_cast<__hip_bfloat16*>(&ldsP[swz256(ql, kl * 2)]) = __float2bfloat16(s);
        }
    // MID: retires carry-stores(32) + V_t(4) + K_{t+1}(4); P visible via lgkm
    barrier_vm32();

    // PV: ctx += P[128q x 128k] * V[128k x 128hd]; wave = 32q x 64hd
    __builtin_amdgcn_s_setprio(1);
#pragma unroll
    for (int kk = 0; kk < 4; ++kk) {
      bf16x8 pf[2], vf[4];
#pragma unroll
      for (int m = 0; m < 2; ++m)
        pf[m] = *reinterpret_cast<const bf16x8*>(
            &ldsP[swz256(wqq + m * 16 + lrow, (kk * 32 + lko) * 2)]);
#pragma unroll
      for (int n = 0; n < 4; ++n)
        vf[n] = *reinterpret_cast<const bf16x8*>(
            &ldsV[swz256(whd + n * 16 + lrow, (kk * 32 + lko) * 2)]);
#pragma unroll
      for (int m = 0; m < 2; ++m)
#pragma unroll
        for (int n = 0; n < 4; ++n)
          cacc[m][n] = __builtin_amdgcn_mfma_f32_16x16x32_bf16(pf[m], vf[n], cacc[m][n], 0, 0, 0);
    }
    __builtin_amdgcn_s_setprio(0);
    // END: DS drained (QK/PV reads, P writes) -> next iter staging WAR-safe;
    // attn stores stay in flight (retired at next MID's vmcnt(32)).
    barrier_lgkm();
  }

  // ctx bf16 [b][s][h*128+hd]
  const int bb = bh >> 3, h = bh & 7;
#pragma unroll
  for (int m = 0; m < 2; ++m)
#pragma unroll
    for (int n = 0; n < 4; ++n)
#pragma unroll
      for (int r = 0; r < 4; ++r) {
        const int srow = q0 + wqq + m * 16 + rbase + r;
        const int hd = whd + n * 16 + lrow;
        ctx[((size_t)(bb * SEQ + srow)) * D_MODEL + h * HDIM + hd] =
            __float2bfloat16(cacc[m][n][r]);
      }
}

extern "C" void kernel_launch(void* const* d_in, const int* in_sizes, int n_in,
                              void* d_out, int out_size, void* d_ws, size_t ws_size,
                              hipStream_t stream) {
  const float* q  = (const float*)d_in[0];
  const float* k  = (const float*)d_in[1];
  const float* v  = (const float*)d_in[2];
  const float* Wq = (const float*)d_in[3];
  const float* bq = (const float*)d_in[4];
  const float* Wk = (const float*)d_in[5];
  const float* bk = (const float*)d_in[6];
  const float* Wv = (const float*)d_in[7];
  const float* bv = (const float*)d_in[8];
  const float* Wo = (const float*)d_in[9];
  const float* bo = (const float*)d_in[10];

  char* ws = (char*)d_ws;
  const size_t NE = (size_t)MTOT * D_MODEL;     // 4194304
  const size_t WE = (size_t)D_MODEL * D_MODEL;  // 1048576
  __hip_bfloat16* qb  = (__hip_bfloat16*)ws;
  __hip_bfloat16* kb  = qb + NE;
  __hip_bfloat16* vb  = kb + NE;
  __hip_bfloat16* Wqt = vb + NE;
  __hip_bfloat16* Wkt = Wqt + WE;
  __hip_bfloat16* Wvt = Wkt + WE;
  __hip_bfloat16* Wot = Wvt + WE;
  __hip_bfloat16* Qh  = Wot + WE;
  __hip_bfloat16* Kh  = Qh + NE;
  __hip_bfloat16* Vt  = Kh + NE;
  __hip_bfloat16* ctx = Vt + NE;

  prep<<<10240, 256, 0, stream>>>(q, k, v, qb, Wq, Wk, Wv, Wo, Wqt, Wkt, Wvt, Wot);

  GemmArgs gq{qb, Wqt, bq, Qh, 0};
  GemmArgs gk{kb, Wkt, bk, Kh, 0};
  GemmArgs gv{vb, Wvt, bv, Vt, 1};
  gemm_gl<<<dim3(32, 8, 3), 256, 0, stream>>>(gq, gk, gv, D_MODEL);

  float* outp  = (float*)d_out;
  float* attnp = outp + NE;
  attn_v6<<<256, 512, 0, stream>>>(Qh, Kh, Vt, attnp, ctx);

  GemmArgs go{ctx, Wot, bo, d_out, 2};
  gemm_gl<<<dim3(32, 8, 1), 256, 0, stream>>>(go, go, go, D_MODEL);
}

// Round 16
// 143.597 us; speedup vs baseline: 1.0691x; 1.0034x over previous
//
#include <hip/hip_runtime.h>
#include <hip/hip_bf16.h>
#include <stdint.h>

#define D_MODEL 1024
#define NHEAD 8
#define HDIM 128
#define BATCH 2
#define SEQ 2048
#define MTOT (BATCH*SEQ)   // 4096
#define KVBLK 128
#define NT (SEQ/KVBLK)     // 16

typedef __attribute__((ext_vector_type(4))) float f32x4;
typedef __attribute__((ext_vector_type(8))) short bf16x8;

// XOR swizzle: LDS(row, c) holds element (row, c ^ ((row&7)<<4)). Involution,
// used identically on the pre-swizzled global source and the ds_read side (G21).
__device__ __forceinline__ uint32_t swz128(uint32_t row, uint32_t cb) {
  return row * 128u + (cb ^ ((row & 7u) << 4));
}
__device__ __forceinline__ uint32_t swz256(uint32_t row, uint32_t cb) {
  return row * 256u + (cb ^ ((row & 7u) << 4));
}

// async global->LDS, 16B per lane
__device__ __forceinline__ void gload16(void* lds, const void* g) {
  __builtin_amdgcn_global_load_lds(
      reinterpret_cast<const __attribute__((address_space(1))) uint32_t*>(
          reinterpret_cast<uintptr_t>(g)),
      reinterpret_cast<__attribute__((address_space(3))) uint32_t*>(
          (uint32_t)reinterpret_cast<uintptr_t>(lds)),
      16, 0, 0);
}

// Counted barriers (T4).
__device__ __forceinline__ void barrier_lgkm() {
  asm volatile("s_waitcnt lgkmcnt(0)\n\ts_barrier" ::: "memory");
}
// attn mid barrier: retire carry stores (32) + this iter's 8 gloads
__device__ __forceinline__ void barrier_vm32() {
  asm volatile("s_waitcnt vmcnt(32) lgkmcnt(0)\n\ts_barrier" ::: "memory");
}
__device__ __forceinline__ void barrier_vm0() {
  asm volatile("s_waitcnt vmcnt(0) lgkmcnt(0)\n\ts_barrier" ::: "memory");
}

// ---------------- prep: cast q/k/v fp32->bf16 (blocks [0,6144)) AND
// transpose+cast 4 weights (blocks [6144,10240)), one launch ----------------
__global__ __launch_bounds__(256)
void prep(const float* __restrict__ q, const float* __restrict__ k,
          const float* __restrict__ v, __hip_bfloat16* __restrict__ qkv_out,
          const float* __restrict__ w0, const float* __restrict__ w1,
          const float* __restrict__ w2, const float* __restrict__ w3,
          __hip_bfloat16* __restrict__ t0, __hip_bfloat16* __restrict__ t1,
          __hip_bfloat16* __restrict__ t2, __hip_bfloat16* __restrict__ t3) {
  const int bid = blockIdx.x;
  const int tid = threadIdx.x;
  if (bid < 6144) {
    const int which = bid >> 11;          // 0..2
    const int blk = bid & 2047;
    const float* src = which == 0 ? q : (which == 1 ? k : v);
    const size_t NE = (size_t)MTOT * D_MODEL;
    size_t i = ((size_t)blk * 256 + tid) * 8;
    float4 a = *reinterpret_cast<const float4*>(src + i);
    float4 b = *reinterpret_cast<const float4*>(src + i + 4);
    __hip_bfloat16 o[8] = {__float2bfloat16(a.x), __float2bfloat16(a.y),
                           __float2bfloat16(a.z), __float2bfloat16(a.w),
                           __float2bfloat16(b.x), __float2bfloat16(b.y),
                           __float2bfloat16(b.z), __float2bfloat16(b.w)};
    *reinterpret_cast<uint4*>(qkv_out + which * NE + i) =
        *reinterpret_cast<const uint4*>(o);
  } else {
    const int rb = bid - 6144;
    const int z = rb >> 10;               // 0..3
    const int rem = rb & 1023;
    const float* W = z == 0 ? w0 : z == 1 ? w1 : z == 2 ? w2 : w3;
    __hip_bfloat16* Wt = z == 0 ? t0 : z == 1 ? t1 : z == 2 ? t2 : t3;
    __shared__ float t[32][33];
    const int x = tid & 31, y = tid >> 5;  // 32 x 8
    const int n0 = (rem & 31) * 32, k0 = (rem >> 5) * 32;
#pragma unroll
    for (int i = 0; i < 4; ++i)
      t[y + i * 8][x] = W[(size_t)(k0 + y + i * 8) * D_MODEL + n0 + x];
    __syncthreads();
#pragma unroll
    for (int i = 0; i < 4; ++i)
      Wt[(size_t)(n0 + y + i * 8) * D_MODEL + k0 + x] = __float2bfloat16(t[x][y + i * 8]);
  }
}

struct GemmArgs {
  const __hip_bfloat16* A;   // [M][K]
  const __hip_bfloat16* B;   // [N][K]  (W^T)
  const float* bias;         // [N]
  void* out;
  int mode;  // 0: bf16 [bh][s][hd]; 1: bf16 [bh][hd][s] (LDS-transposed store)
};

// ---------------- 128x128 bf16 GEMM, double-buffered prefetch K-loop (r8-proven) ----------------
// QKV projections (3 blocks/CU regime). mode-1 epilogue: LDS-transpose (r13-proven).
__global__ __launch_bounds__(256)
void gemm_gl(GemmArgs g0, GemmArgs g1, GemmArgs g2, int K) {
  __shared__ char lds[2][32768];   // per buf: A 16KB | B 16KB
  GemmArgs ga = blockIdx.z == 0 ? g0 : (blockIdx.z == 1 ? g1 : g2);

  const int tid = threadIdx.x, lane = tid & 63, wid = tid >> 6;
  const int lrow = lane & 15, lko = (lane >> 4) * 8, rbase = (lane >> 4) * 4;
  const int m0 = blockIdx.x * 128, n0 = blockIdx.y * 128;
  const size_t ldb = (size_t)K * 2;

  const int srow = lane >> 3;                       // row within 8-row call (row&7 const per lane)
  const int sca = ((lane & 7) * 16) ^ (srow << 4);  // pre-swizzled source col
  const char* Ab = (const char*)ga.A + (size_t)(m0 + wid * 32 + srow) * ldb + sca;
  const char* Bb = (const char*)ga.B + (size_t)(n0 + wid * 32 + srow) * ldb + sca;
  const int sdst = wid * 32 * 128;                  // wave's LDS row base (bytes)

  f32x4 acc[4][4];
  const f32x4 fz = {0.f, 0.f, 0.f, 0.f};
#pragma unroll
  for (int m = 0; m < 4; ++m)
#pragma unroll
    for (int n = 0; n < 4; ++n) acc[m][n] = fz;

  const int wm = (wid >> 1) * 64, wn = (wid & 1) * 64;
  const int NKT = K >> 6;

  // prologue: stage tile 0 into buf 0
#pragma unroll
  for (int i = 0; i < 4; ++i) {
    gload16(&lds[0][sdst + i * 8 * 128], Ab + (size_t)i * 8 * ldb);
    gload16(&lds[0][16384 + sdst + i * 8 * 128], Bb + (size_t)i * 8 * ldb);
  }
  barrier_vm0();   // tile 0 ready

  for (int kt = 0; kt < NKT; ++kt) {
    const int c = kt & 1;
    if (kt + 1 < NKT) {  // prefetch next tile into other buffer
      const size_t koff = (size_t)(kt + 1) * 128;
#pragma unroll
      for (int i = 0; i < 4; ++i) {
        gload16(&lds[c ^ 1][sdst + i * 8 * 128], Ab + (size_t)i * 8 * ldb + koff);
        gload16(&lds[c ^ 1][16384 + sdst + i * 8 * 128], Bb + (size_t)i * 8 * ldb + koff);
      }
    }
    const char* lA = lds[c];
    const char* lB = lds[c] + 16384;
#pragma unroll
    for (int kk = 0; kk < 64; kk += 32) {
      bf16x8 af[4], bf[4];
#pragma unroll
      for (int m = 0; m < 4; ++m)
        af[m] = *reinterpret_cast<const bf16x8*>(&lA[swz128(wm + m * 16 + lrow, (kk + lko) * 2)]);
#pragma unroll
      for (int n = 0; n < 4; ++n)
        bf[n] = *reinterpret_cast<const bf16x8*>(&lB[swz128(wn + n * 16 + lrow, (kk + lko) * 2)]);
      __builtin_amdgcn_s_setprio(1);
#pragma unroll
      for (int m = 0; m < 4; ++m)
#pragma unroll
        for (int n = 0; n < 4; ++n)
          acc[m][n] = __builtin_amdgcn_mfma_f32_16x16x32_bf16(af[m], bf[n], acc[m][n], 0, 0, 0);
      __builtin_amdgcn_s_setprio(0);
    }
    barrier_vm0();  // prefetch complete + all ds_reads retired -> bufs swap safely
  }

  if (ga.mode == 0) {
#pragma unroll
    for (int m = 0; m < 4; ++m)
#pragma unroll
      for (int n = 0; n < 4; ++n) {
        const int col = n0 + wn + n * 16 + lrow;
        const float bv = ga.bias[col];
        const int h = col >> 7, hd = col & 127;
#pragma unroll
        for (int r = 0; r < 4; ++r) {
          const int row = m0 + wm + m * 16 + rbase + r;
          const int b = row >> 11, s = row & 2047;
          reinterpret_cast<__hip_bfloat16*>(ga.out)[((size_t)(b * NHEAD + h) * SEQ + s) * HDIM + hd] =
              __float2bfloat16(acc[m][n][r] + bv);
        }
      }
  } else {
    // mode 1: Vt[bh][hd][s] via LDS transpose -> coalesced 256B-row stores.
    char* T = lds[0];  // 32KB: [hd 128][s 128] bf16, swz256 rows
#pragma unroll
    for (int m = 0; m < 4; ++m)
#pragma unroll
      for (int n = 0; n < 4; ++n) {
        const int hdl = wn + n * 16 + lrow;
        const float bv = ga.bias[n0 + hdl];
#pragma unroll
        for (int r = 0; r < 4; ++r) {
          const int sl = wm + m * 16 + rbase + r;
          *reinterpret_cast<__hip_bfloat16*>(&T[swz256(hdl, sl * 2)]) =
              __float2bfloat16(acc[m][n][r] + bv);
        }
      }
    __syncthreads();
    const int b = m0 >> 11, h = n0 >> 7;   // block spans one b and one head
    char* vtb = (char*)ga.out +
                (((size_t)(b * NHEAD + h) * HDIM) * SEQ + (m0 & 2047)) * 2;
    const int lr16 = tid >> 4;             // row within pass (0..15)
    const int lc16 = (tid & 15) * 16;      // byte col within 256B row
#pragma unroll
    for (int p = 0; p < 8; ++p) {
      const int hdl = p * 16 + lr16;
      uint4 vv = *reinterpret_cast<const uint4*>(&T[swz256(hdl, lc16)]);
      *reinterpret_cast<uint4*>(vtb + (size_t)hdl * (SEQ * 2) + lc16) = vv;
    }
  }
}

// ---------------- out-projection GEMM: 128x128 tile, BK=128 (r14 lever) ----------------
// grid 256 = exactly 1 block/CU either way, so 128KB LDS costs nothing.
// Per K-tile per wave: 64 MFMA between barriers (2x r8), 8 barriers (vs 16).
// FIX vs r15: staging uses 4-row (1KB) calls, so the source swizzle row parity
// includes j*4 — swizzle recomputed per call: scb ^ ((srl + 4*(j&1))<<4).
__global__ __launch_bounds__(256)
void gemm_o(const __hip_bfloat16* __restrict__ A,   // [M][K] (ctx)
            const __hip_bfloat16* __restrict__ Bt,  // [N][K] (Wo^T)
            const float* __restrict__ bias,
            float* __restrict__ out, int K) {
  __shared__ char lds[2][65536];   // per buf: A 32KB | B 32KB, rows 256B

  const int tid = threadIdx.x, lane = tid & 63, wid = tid >> 6;
  const int lrow = lane & 15, lko = (lane >> 4) * 8, rbase = (lane >> 4) * 4;
  const int m0 = blockIdx.x * 128, n0 = blockIdx.y * 128;
  const size_t ldb = (size_t)K * 2;

  const int srl = lane >> 4;                         // row within 4-row (1KB) call
  const int scb = (lane & 15) * 16;                  // byte col within 256B row
  // base pointers WITHOUT swizzle column (added per call with correct row parity)
  const char* Ab = (const char*)A + (size_t)(m0 + wid * 32 + srl) * ldb;
  const char* Bb = (const char*)Bt + (size_t)(n0 + wid * 32 + srl) * ldb;
  const int sdst = wid * 32 * 256;                   // wave's LDS row base (bytes)

  f32x4 acc[4][4];
  const f32x4 fz = {0.f, 0.f, 0.f, 0.f};
#pragma unroll
  for (int m = 0; m < 4; ++m)
#pragma unroll
    for (int n = 0; n < 4; ++n) acc[m][n] = fz;

  const int wm = (wid >> 1) * 64, wn = (wid & 1) * 64;
  const int NKT = K >> 7;   // 8

  // prologue: stage tile 0 into buf 0 (per wave: 32 rows x 256B = 8 calls each op)
#pragma unroll
  for (int j = 0; j < 8; ++j) {
    const int sw = scb ^ ((srl + 4 * (j & 1)) << 4);   // row = wid*32 + j*4 + srl; (row&7) = srl + 4*(j&1)
    gload16(&lds[0][sdst + j * 1024], Ab + (size_t)(j * 4) * ldb + sw);
    gload16(&lds[0][32768 + sdst + j * 1024], Bb + (size_t)(j * 4) * ldb + sw);
  }
  barrier_vm0();   // tile 0 ready

  for (int kt = 0; kt < NKT; ++kt) {
    const int c = kt & 1;
    if (kt + 1 < NKT) {  // prefetch next 128-deep tile into other buffer
      const size_t koff = (size_t)(kt + 1) * 256;
#pragma unroll
      for (int j = 0; j < 8; ++j) {
        const int sw = scb ^ ((srl + 4 * (j & 1)) << 4);
        gload16(&lds[c ^ 1][sdst + j * 1024], Ab + (size_t)(j * 4) * ldb + koff + sw);
        gload16(&lds[c ^ 1][32768 + sdst + j * 1024], Bb + (size_t)(j * 4) * ldb + koff + sw);
      }
    }
    const char* lA = lds[c];
    const char* lB = lds[c] + 32768;
#pragma unroll
    for (int kk = 0; kk < 128; kk += 32) {
      bf16x8 af[4], bf[4];
#pragma unroll
      for (int m = 0; m < 4; ++m)
        af[m] = *reinterpret_cast<const bf16x8*>(&lA[swz256(wm + m * 16 + lrow, (kk + lko) * 2)]);
#pragma unroll
      for (int n = 0; n < 4; ++n)
        bf[n] = *reinterpret_cast<const bf16x8*>(&lB[swz256(wn + n * 16 + lrow, (kk + lko) * 2)]);
      __builtin_amdgcn_s_setprio(1);
#pragma unroll
      for (int m = 0; m < 4; ++m)
#pragma unroll
        for (int n = 0; n < 4; ++n)
          acc[m][n] = __builtin_amdgcn_mfma_f32_16x16x32_bf16(af[m], bf[n], acc[m][n], 0, 0, 0);
      __builtin_amdgcn_s_setprio(0);
    }
    barrier_vm0();  // prefetch complete + ds_reads retired
  }

#pragma unroll
  for (int m = 0; m < 4; ++m)
#pragma unroll
    for (int n = 0; n < 4; ++n) {
      const int col = n0 + wn + n * 16 + lrow;
      const float bv = bias[col];
#pragma unroll
      for (int r = 0; r < 4; ++r) {
        const int row = m0 + wm + m * 16 + rbase + r;
        out[(size_t)row * D_MODEL + col] = acc[m][n][r] + bv;
      }
    }
}

// ---------------- fused ReLU attention v6 (r14-proven): KVBLK=128 ----------------
__global__ __launch_bounds__(512)
void attn_v6(const __hip_bfloat16* __restrict__ Qh,   // [bh][s][hd]
             const __hip_bfloat16* __restrict__ Kh,   // [bh][s][hd]
             const __hip_bfloat16* __restrict__ Vt,   // [bh][hd][s]
             float* __restrict__ attn,                // [bh][q][k]
             __hip_bfloat16* __restrict__ ctx) {      // [b][s][h*128+hd]
  __shared__ char ldsK[2][KVBLK * 256];   // 2 x 32KB
  __shared__ char ldsV[HDIM * 256];       // 32KB
  __shared__ char ldsP[128 * 256];        // 32KB

  const int tid = threadIdx.x, lane = tid & 63, wid = tid >> 6;
  const int lrow = lane & 15, lko = (lane >> 4) * 8, rbase = (lane >> 4) * 4;
  const int wqq = (wid >> 1) * 32;   // q offset (4 groups)
  const int wqk = (wid & 1) * 64;    // key half in QK
  const int whd = (wid & 1) * 64;    // hd half in PV

  const int raw = blockIdx.x;
  const int xcd = raw & 7, slot = raw >> 3;
  const int bh = xcd * 2 + (slot >> 4);
  const int q0 = (slot & 15) * 128;

  const char* Kg = (const char*)Kh + (size_t)bh * SEQ * HDIM * 2;
  const char* Vg = (const char*)Vt + (size_t)bh * HDIM * SEQ * 2;
  const __hip_bfloat16* Qg = Qh + ((size_t)bh * SEQ + q0) * HDIM;
  float* attnb = attn + ((size_t)bh * SEQ + q0) * SEQ;

  const int srl = lane >> 4;             // row within 4-row (1KB) gload call
  const int scb = (lane & 15) * 16;      // byte col within 256B row

  // prologue: stage K tile 0
#pragma unroll
  for (int j = 0; j < 4; ++j) {
    const int rr = wid * 16 + j * 4 + srl;
    gload16((char*)ldsK[0] + (wid * 16 + j * 4) * 256,
            Kg + (size_t)rr * 256 + (scb ^ ((rr & 7) << 4)));
  }

  // Q -> registers (reused all 16 tiles)
  bf16x8 qf[2][4];
#pragma unroll
  for (int m = 0; m < 2; ++m)
#pragma unroll
    for (int kk = 0; kk < 4; ++kk)
      qf[m][kk] = *reinterpret_cast<const bf16x8*>(
          Qg + (size_t)(wqq + m * 16 + lrow) * HDIM + kk * 32 + lko);

  f32x4 cacc[2][4];
  const f32x4 fz = {0.f, 0.f, 0.f, 0.f};
#pragma unroll
  for (int m = 0; m < 2; ++m)
#pragma unroll
    for (int n = 0; n < 4; ++n) cacc[m][n] = fz;

  const float scale = 0.08838834764831845f;  // 1/sqrt(128)
  __syncthreads();   // full drain: K0 + qf ready

  for (int t = 0; t < NT; ++t) {
    const int b = t & 1;
    // stage V_t (single buffer; prev PV ds_reads drained at prev END barrier)
#pragma unroll
    for (int j = 0; j < 4; ++j) {
      const int rv = wid * 16 + j * 4 + srl;
      gload16((char*)ldsV + (wid * 16 + j * 4) * 256,
              Vg + (size_t)rv * (SEQ * 2) + t * 256 + (scb ^ ((rv & 7) << 4)));
    }
    if (t + 1 < NT) {  // prefetch K tile t+1 into other buffer
#pragma unroll
      for (int j = 0; j < 4; ++j) {
        const int rr = wid * 16 + j * 4 + srl;
        gload16((char*)ldsK[b ^ 1] + (wid * 16 + j * 4) * 256,
                Kg + (size_t)((t + 1) * KVBLK + rr) * 256 + (scb ^ ((rr & 7) << 4)));
      }
    }

    // QK^T: S[128q x 128k]; wave = 32q x 64k
    f32x4 sacc[2][4];
#pragma unroll
    for (int m = 0; m < 2; ++m)
#pragma unroll
      for (int n = 0; n < 4; ++n) sacc[m][n] = fz;
    __builtin_amdgcn_s_setprio(1);
#pragma unroll
    for (int kk = 0; kk < 4; ++kk) {
      bf16x8 kf[4];
#pragma unroll
      for (int n = 0; n < 4; ++n)
        kf[n] = *reinterpret_cast<const bf16x8*>(
            &ldsK[b][swz256(wqk + n * 16 + lrow, (kk * 32 + lko) * 2)]);
#pragma unroll
      for (int m = 0; m < 2; ++m)
#pragma unroll
        for (int n = 0; n < 4; ++n)
          sacc[m][n] = __builtin_amdgcn_mfma_f32_16x16x32_bf16(qf[m][kk], kf[n], sacc[m][n], 0, 0, 0);
    }
    __builtin_amdgcn_s_setprio(0);

    // scale + relu -> global fp32 attn (32 stores/wave, left in flight) + bf16 P
#pragma unroll
    for (int m = 0; m < 2; ++m)
#pragma unroll
      for (int n = 0; n < 4; ++n)
#pragma unroll
        for (int r = 0; r < 4; ++r) {
          const int ql = wqq + m * 16 + rbase + r;
          const int kl = wqk + n * 16 + lrow;
          const float s = fmaxf(sacc[m][n][r] * scale, 0.f);
          attnb[(size_t)ql * SEQ + t * KVBLK + kl] = s;
          *reinterpret_cast<__hip_bfloat16*>(&ldsP[swz256(ql, kl * 2)]) = __float2bfloat16(s);
        }
    // MID: retires carry-stores(32) + V_t(4) + K_{t+1}(4); P visible via lgkm
    barrier_vm32();

    // PV: ctx += P[128q x 128k] * V[128k x 128hd]; wave = 32q x 64hd
    __builtin_amdgcn_s_setprio(1);
#pragma unroll
    for (int kk = 0; kk < 4; ++kk) {
      bf16x8 pf[2], vf[4];
#pragma unroll
      for (int m = 0; m < 2; ++m)
        pf[m] = *reinterpret_cast<const bf16x8*>(
            &ldsP[swz256(wqq + m * 16 + lrow, (kk * 32 + lko) * 2)]);
#pragma unroll
      for (int n = 0; n < 4; ++n)
        vf[n] = *reinterpret_cast<const bf16x8*>(
            &ldsV[swz256(whd + n * 16 + lrow, (kk * 32 + lko) * 2)]);
#pragma unroll
      for (int m = 0; m < 2; ++m)
#pragma unroll
        for (int n = 0; n < 4; ++n)
          cacc[m][n] = __builtin_amdgcn_mfma_f32_16x16x32_bf16(pf[m], vf[n], cacc[m][n], 0, 0, 0);
    }
    __builtin_amdgcn_s_setprio(0);
    // END: DS drained -> next iter staging WAR-safe; stores stay in flight.
    barrier_lgkm();
  }

  // ctx bf16 [b][s][h*128+hd]
  const int bb = bh >> 3, h = bh & 7;
#pragma unroll
  for (int m = 0; m < 2; ++m)
#pragma unroll
    for (int n = 0; n < 4; ++n)
#pragma unroll
      for (int r = 0; r < 4; ++r) {
        const int srow = q0 + wqq + m * 16 + rbase + r;
        const int hd = whd + n * 16 + lrow;
        ctx[((size_t)(bb * SEQ + srow)) * D_MODEL + h * HDIM + hd] =
            __float2bfloat16(cacc[m][n][r]);
      }
}

extern "C" void kernel_launch(void* const* d_in, const int* in_sizes, int n_in,
                              void* d_out, int out_size, void* d_ws, size_t ws_size,
                              hipStream_t stream) {
  const float* q  = (const float*)d_in[0];
  const float* k  = (const float*)d_in[1];
  const float* v  = (const float*)d_in[2];
  const float* Wq = (const float*)d_in[3];
  const float* bq = (const float*)d_in[4];
  const float* Wk = (const float*)d_in[5];
  const float* bk = (const float*)d_in[6];
  const float* Wv = (const float*)d_in[7];
  const float* bv = (const float*)d_in[8];
  const float* Wo = (const float*)d_in[9];
  const float* bo = (const float*)d_in[10];

  char* ws = (char*)d_ws;
  const size_t NE = (size_t)MTOT * D_MODEL;     // 4194304
  const size_t WE = (size_t)D_MODEL * D_MODEL;  // 1048576
  __hip_bfloat16* qb  = (__hip_bfloat16*)ws;
  __hip_bfloat16* kb  = qb + NE;
  __hip_bfloat16* vb  = kb + NE;
  __hip_bfloat16* Wqt = vb + NE;
  __hip_bfloat16* Wkt = Wqt + WE;
  __hip_bfloat16* Wvt = Wkt + WE;
  __hip_bfloat16* Wot = Wvt + WE;
  __hip_bfloat16* Qh  = Wot + WE;
  __hip_bfloat16* Kh  = Qh + NE;
  __hip_bfloat16* Vt  = Kh + NE;
  __hip_bfloat16* ctx = Vt + NE;

  prep<<<10240, 256, 0, stream>>>(q, k, v, qb, Wq, Wk, Wv, Wo, Wqt, Wkt, Wvt, Wot);

  GemmArgs gq{qb, Wqt, bq, Qh, 0};
  GemmArgs gk{kb, Wkt, bk, Kh, 0};
  GemmArgs gv{vb, Wvt, bv, Vt, 1};
  gemm_gl<<<dim3(32, 8, 3), 256, 0, stream>>>(gq, gk, gv, D_MODEL);

  float* outp  = (float*)d_out;
  float* attnp = outp + NE;
  attn_v6<<<256, 512, 0, stream>>>(Qh, Kh, Vt, attnp, ctx);

  gemm_o<<<dim3(32, 8), 256, 0, stream>>>(ctx, Wot, bo, (float*)d_out, D_MODEL);
}